// Round 2
// baseline (445.740 us; speedup 1.0000x reference)
//
#include <hip/hip_runtime.h>

// Problem constants
#define BATCH 16
#define CH 64          // EMBEDDING_DIM
#define HW 4096        // 64*64
#define NPIX 65536     // BATCH*HW
#define KCODES 512
#define DDIM 64
#define NELEM 4194304  // NPIX*CH

// d_out layout (float32): [z_q_st: NELEM][loss: 1][ppl: 1][indices: NPIX]
#define OUT_LOSS 4194304
#define OUT_PPL  4194305
#define OUT_IDX  4194306

#define MARGIN 1e-4f

// Force a value to be materialized (blocks fp-contract fusing mul into add,
// so squares round exactly like numpy's materialized flat*flat).
__device__ __forceinline__ float rnd(float s) {
    asm volatile("" : "+v"(s));
    return s;
}

// -------------------- prep: ||e_k||^2, numpy pairwise order --------------------
__global__ void prep_e2(const float* __restrict__ emb, float* __restrict__ e2) {
    int k = blockIdx.x * blockDim.x + threadIdx.x;
    if (k < KCODES) {
        const float* row = emb + k * DDIM;
        float r[8];
        #pragma unroll
        for (int j = 0; j < 8; ++j) { float v = row[j]; r[j] = rnd(v * v); }
        #pragma unroll
        for (int m = 1; m < 8; ++m)
            #pragma unroll
            for (int j = 0; j < 8; ++j) { float v = row[8 * m + j]; r[j] += rnd(v * v); }
        e2[k] = ((r[0] + r[1]) + (r[2] + r[3])) + ((r[4] + r[5]) + (r[6] + r[7]));
    }
}

// -------------------- main distance/argmin kernel --------------------
// Block = 256 threads = 128 pixels x 2 K-halves.
__global__ __launch_bounds__(256, 2) void k_dist(
        const float* __restrict__ z_e, const float* __restrict__ emb,
        const float* __restrict__ e2,
        int* __restrict__ idx, int* __restrict__ flags, int* __restrict__ nflag) {
    __shared__ float s_m1[128], s_m2[128];
    __shared__ int   s_i1[128];

    int tid = threadIdx.x;
    int half = __builtin_amdgcn_readfirstlane(tid >> 7);  // wave-uniform
    int lp = tid & 127;
    int g = blockIdx.x * 128 + lp;          // pixel id
    int b = g >> 12;
    int p = g & 4095;
    const float* xp = z_e + (size_t)b * (CH * HW) + p;

    float x[DDIM];
    #pragma unroll
    for (int c = 0; c < DDIM; ++c) x[c] = xp[c * HW];

    float m1 = 1e30f, m2 = 1e30f;
    int i1 = 0;
    int k0 = half * 256;

    for (int kk = 0; kk < 256; kk += 2) {
        int k = k0 + kk;
        const float* r0 = emb + k * DDIM;          // wave-uniform -> s_load
        const float* r1 = r0 + DDIM;
        float a0 = 0.f, a1 = 0.f, b0 = 0.f, b1 = 0.f;
        #pragma unroll
        for (int c = 0; c < DDIM; c += 2) {
            a0 = fmaf(x[c],     r0[c],     a0);
            a1 = fmaf(x[c + 1], r0[c + 1], a1);
            b0 = fmaf(x[c],     r1[c],     b0);
            b1 = fmaf(x[c + 1], r1[c + 1], b1);
        }
        float d0 = fmaf(-2.0f, a0 + a1, e2[k]);
        float d1 = fmaf(-2.0f, b0 + b1, e2[k + 1]);
        if (d0 < m1)      { m2 = m1; m1 = d0; i1 = k; }
        else if (d0 < m2) { m2 = d0; }
        if (d1 < m1)      { m2 = m1; m1 = d1; i1 = k + 1; }
        else if (d1 < m2) { m2 = d1; }
    }

    if (half == 1) { s_m1[lp] = m1; s_m2[lp] = m2; s_i1[lp] = i1; }
    __syncthreads();
    if (half == 0) {
        float om1 = s_m1[lp], om2 = s_m2[lp];
        int   oi1 = s_i1[lp];
        float gm1, gm2; int gi1;
        if (m1 <= om1) { gm1 = m1;  gi1 = i1;  gm2 = fminf(m2, om1); }
        else           { gm1 = om1; gi1 = oi1; gm2 = fminf(m1, om2); }
        idx[g] = gi1;
        if (gm2 - gm1 < MARGIN) {
            int pos = atomicAdd(nflag, 1);
            flags[pos] = g;
        }
    }
}

// -------------------- near-tie refinement: simulate numpy fp32 exactly --------------------
// d_np = fp32( fp32(x2 + e2np[k]) - 2*fp32(dot) ), argmin first-occurrence.
// x2 via numpy pairwise pattern; dot in fp64 rounded to fp32 (~sgemm accuracy).
__global__ __launch_bounds__(256) void k_refine(
        const float* __restrict__ z_e, const float* __restrict__ emb,
        const float* __restrict__ e2,
        int* __restrict__ idx, const int* __restrict__ flags,
        const int* __restrict__ nflag) {
    int n = nflag[0];
    int wave = (blockIdx.x * blockDim.x + threadIdx.x) >> 6;
    int lane = threadIdx.x & 63;
    int nwaves = (gridDim.x * blockDim.x) >> 6;

    for (int i = wave; i < n; i += nwaves) {
        int g = flags[i];
        int b = g >> 12;
        int p = g & 4095;
        const float* xp = z_e + (size_t)b * (CH * HW) + p;
        float x[DDIM];
        #pragma unroll
        for (int c = 0; c < DDIM; ++c) x[c] = xp[c * HW];

        // numpy pairwise sum of squares (n=64: 8 accumulators + tree combine)
        float r[8];
        #pragma unroll
        for (int j = 0; j < 8; ++j) r[j] = rnd(x[j] * x[j]);
        #pragma unroll
        for (int m = 1; m < 8; ++m)
            #pragma unroll
            for (int j = 0; j < 8; ++j) r[j] += rnd(x[8 * m + j] * x[8 * m + j]);
        float x2 = ((r[0] + r[1]) + (r[2] + r[3])) + ((r[4] + r[5]) + (r[6] + r[7]));

        float bestd = INFINITY;
        int besti = 1 << 30;
        for (int kk = 0; kk < 8; ++kk) {
            int k = lane * 8 + kk;
            const float* row = emb + k * DDIM;
            double dot = 0.0;
            #pragma unroll
            for (int c = 0; c < DDIM; ++c) dot = fma((double)x[c], (double)row[c], dot);
            float dotf = (float)dot;                  // == sgemm M within ~1e-9
            float t = x2 + e2[k];                     // fp32 add (quantizes at ulp(~64))
            float d = t - 2.0f * dotf;                // 2*dotf exact; one rounding
            if (d < bestd) { bestd = d; besti = k; }  // ascending k: first wins ties
        }
        // cross-lane min-reduce, tie -> smaller index (np.argmin first occurrence)
        for (int off = 32; off; off >>= 1) {
            double od_ = __shfl_down(bestd, off);
            float od = (float)od_;
            int   oi = __shfl_down(besti, off);
            if (od < bestd || (od == bestd && oi < besti)) { bestd = od; besti = oi; }
        }
        if (lane == 0) idx[g] = besti;
    }
}

// -------------------- epilogue: z_q_st, loss partials, histogram, indices --------------------
__global__ __launch_bounds__(256) void k_epilogue(
        const float* __restrict__ z_e, const float* __restrict__ emb,
        const int* __restrict__ idx, float* __restrict__ out,
        int* __restrict__ counts, float* __restrict__ loss_sum) {
    int e = blockIdx.x * 256 + threadIdx.x;   // grid exactly covers NELEM
    int p = e & 4095;
    int c = (e >> 12) & 63;
    int b = e >> 18;
    int g = (b << 12) | p;

    int i = idx[g];
    float q  = emb[i * DDIM + c];
    float ze = z_e[e];
    float diff = q - ze;                      // stop_gradient(z_q - z_e)
    out[e] = ze + diff;                       // straight-through z_q_st

    if (c == 0) {
        atomicAdd(&counts[i], 1);
        out[OUT_IDX + g] = (float)i;
    }

    float sq = diff * diff;
    #pragma unroll
    for (int off = 32; off; off >>= 1) sq += __shfl_down(sq, off);
    __shared__ float ls[4];
    int lane = threadIdx.x & 63, w = threadIdx.x >> 6;
    if (lane == 0) ls[w] = sq;
    __syncthreads();
    if (threadIdx.x == 0) {
        atomicAdd(loss_sum, ls[0] + ls[1] + ls[2] + ls[3]);
    }
}

// -------------------- final scalars: loss, perplexity --------------------
__global__ void k_final(const int* __restrict__ counts,
                        const float* __restrict__ loss_sum,
                        float* __restrict__ out) {
    int t = threadIdx.x;  // 512 threads, 1 block
    float cnt = (float)counts[t];
    float pb = cnt * (1.0f / 65536.0f);
    float term = pb * logf(pb + 1e-10f);
    #pragma unroll
    for (int off = 32; off; off >>= 1) term += __shfl_down(term, off);
    __shared__ float ls[8];
    int lane = t & 63, w = t >> 6;
    if (lane == 0) ls[w] = term;
    __syncthreads();
    if (t == 0) {
        float s = 0.0f;
        #pragma unroll
        for (int i = 0; i < 8; ++i) s += ls[i];
        out[OUT_PPL]  = expf(-s);
        out[OUT_LOSS] = 0.25f * (loss_sum[0] / (float)NELEM);
    }
}

extern "C" void kernel_launch(void* const* d_in, const int* in_sizes, int n_in,
                              void* d_out, int out_size, void* d_ws, size_t ws_size,
                              hipStream_t stream) {
    const float* z_e = (const float*)d_in[0];
    const float* emb = (const float*)d_in[1];
    float* out = (float*)d_out;
    char* ws = (char*)d_ws;

    // ws layout
    int*   idx      = (int*)(ws);             // 65536 ints   [0, 262144)
    int*   flags    = (int*)(ws + 262144);    // 65536 ints   [262144, 524288)
    float* e2       = (float*)(ws + 524288);  // 512 floats   [524288, 526336)
    int*   nflag    = (int*)(ws + 526336);    // 1 int
    int*   counts   = (int*)(ws + 526400);    // 512 ints     [526400, 528448)
    float* loss_sum = (float*)(ws + 528448);  // 1 float

    // zero the accumulators (ws is poisoned 0xAA before every timed launch)
    hipMemsetAsync(ws + 526336, 0, 528452 - 526336, stream);

    prep_e2<<<1, 512, 0, stream>>>(emb, e2);
    k_dist<<<NPIX / 128, 256, 0, stream>>>(z_e, emb, e2, idx, flags, nflag);
    k_refine<<<256, 256, 0, stream>>>(z_e, emb, e2, idx, flags, nflag);
    k_epilogue<<<NELEM / 256, 256, 0, stream>>>(z_e, emb, idx, out, counts, loss_sum);
    k_final<<<1, 512, 0, stream>>>(counts, loss_sum, out);
}

// Round 3
// 259.058 us; speedup vs baseline: 1.7206x; 1.7206x over previous
//
#include <hip/hip_runtime.h>

// Problem constants
#define BATCH 16
#define CH 64          // EMBEDDING_DIM
#define HW 4096        // 64*64
#define NPIX 65536     // BATCH*HW
#define KCODES 512
#define DDIM 64
#define NELEM 4194304  // NPIX*CH

// d_out layout (float32): [z_q_st: NELEM][loss: 1][ppl: 1][indices: NPIX]
#define OUT_LOSS 4194304
#define OUT_PPL  4194305
#define OUT_IDX  4194306

#define MARGIN 1e-4f

// Force a value to be materialized (blocks fp-contract fusing mul into add,
// so squares round exactly like numpy's materialized flat*flat).
__device__ __forceinline__ float rnd(float s) {
    asm volatile("" : "+v"(s));
    return s;
}

// -------------------- prep: ||e_k||^2, numpy pairwise order --------------------
__global__ void prep_e2(const float* __restrict__ emb, float* __restrict__ e2) {
    int k = blockIdx.x * blockDim.x + threadIdx.x;
    if (k < KCODES) {
        const float* row = emb + k * DDIM;
        float r[8];
        #pragma unroll
        for (int j = 0; j < 8; ++j) { float v = row[j]; r[j] = rnd(v * v); }
        #pragma unroll
        for (int m = 1; m < 8; ++m)
            #pragma unroll
            for (int j = 0; j < 8; ++j) { float v = row[8 * m + j]; r[j] += rnd(v * v); }
        e2[k] = ((r[0] + r[1]) + (r[2] + r[3])) + ((r[4] + r[5]) + (r[6] + r[7]));
    }
}

// -------------------- main distance/argmin kernel --------------------
// Block = 256 threads = 128 pixels x 2 K-halves.
__global__ __launch_bounds__(256, 2) void k_dist(
        const float* __restrict__ z_e, const float* __restrict__ emb,
        const float* __restrict__ e2,
        int* __restrict__ idx, int* __restrict__ flags, int* __restrict__ nflag,
        int* __restrict__ counts, float* __restrict__ out) {
    __shared__ float s_m1[128], s_m2[128];
    __shared__ int   s_i1[128];

    int tid = threadIdx.x;
    int half = __builtin_amdgcn_readfirstlane(tid >> 7);  // wave-uniform
    int lp = tid & 127;
    int g = blockIdx.x * 128 + lp;          // pixel id
    int b = g >> 12;
    int p = g & 4095;
    const float* xp = z_e + (size_t)b * (CH * HW) + p;

    float x[DDIM];
    #pragma unroll
    for (int c = 0; c < DDIM; ++c) x[c] = xp[c * HW];

    float m1 = 1e30f, m2 = 1e30f;
    int i1 = 0;
    int k0 = half * 256;

    for (int kk = 0; kk < 256; kk += 2) {
        int k = k0 + kk;
        const float* r0 = emb + k * DDIM;          // wave-uniform -> s_load
        const float* r1 = r0 + DDIM;
        float a0 = 0.f, a1 = 0.f, b0 = 0.f, b1 = 0.f;
        #pragma unroll
        for (int c = 0; c < DDIM; c += 2) {
            a0 = fmaf(x[c],     r0[c],     a0);
            a1 = fmaf(x[c + 1], r0[c + 1], a1);
            b0 = fmaf(x[c],     r1[c],     b0);
            b1 = fmaf(x[c + 1], r1[c + 1], b1);
        }
        float d0 = fmaf(-2.0f, a0 + a1, e2[k]);
        float d1 = fmaf(-2.0f, b0 + b1, e2[k + 1]);
        if (d0 < m1)      { m2 = m1; m1 = d0; i1 = k; }
        else if (d0 < m2) { m2 = d0; }
        if (d1 < m1)      { m2 = m1; m1 = d1; i1 = k + 1; }
        else if (d1 < m2) { m2 = d1; }
    }

    if (half == 1) { s_m1[lp] = m1; s_m2[lp] = m2; s_i1[lp] = i1; }
    __syncthreads();
    if (half == 0) {
        float om1 = s_m1[lp], om2 = s_m2[lp];
        int   oi1 = s_i1[lp];
        float gm1, gm2; int gi1;
        if (m1 <= om1) { gm1 = m1;  gi1 = i1;  gm2 = fminf(m2, om1); }
        else           { gm1 = om1; gi1 = oi1; gm2 = fminf(m1, om2); }
        idx[g] = gi1;
        out[OUT_IDX + g] = (float)gi1;
        atomicAdd(&counts[gi1], 1);
        if (gm2 - gm1 < MARGIN) {
            int pos = atomicAdd(nflag, 1);
            flags[pos] = g;
        }
    }
}

// -------------------- near-tie refinement: simulate numpy fp32 exactly --------------------
// d_np = fp32( fp32(x2 + e2np[k]) - 2*fp32(dot) ), argmin first-occurrence.
__global__ __launch_bounds__(256) void k_refine(
        const float* __restrict__ z_e, const float* __restrict__ emb,
        const float* __restrict__ e2,
        int* __restrict__ idx, const int* __restrict__ flags,
        const int* __restrict__ nflag,
        int* __restrict__ counts, float* __restrict__ out) {
    int n = nflag[0];
    int wave = (blockIdx.x * blockDim.x + threadIdx.x) >> 6;
    int lane = threadIdx.x & 63;
    int nwaves = (gridDim.x * blockDim.x) >> 6;

    for (int i = wave; i < n; i += nwaves) {
        int g = flags[i];
        int b = g >> 12;
        int p = g & 4095;
        const float* xp = z_e + (size_t)b * (CH * HW) + p;
        float x[DDIM];
        #pragma unroll
        for (int c = 0; c < DDIM; ++c) x[c] = xp[c * HW];

        // numpy pairwise sum of squares (n=64: 8 accumulators + tree combine)
        float r[8];
        #pragma unroll
        for (int j = 0; j < 8; ++j) r[j] = rnd(x[j] * x[j]);
        #pragma unroll
        for (int m = 1; m < 8; ++m)
            #pragma unroll
            for (int j = 0; j < 8; ++j) r[j] += rnd(x[8 * m + j] * x[8 * m + j]);
        float x2 = ((r[0] + r[1]) + (r[2] + r[3])) + ((r[4] + r[5]) + (r[6] + r[7]));

        float bestd = INFINITY;
        int besti = 1 << 30;
        for (int kk = 0; kk < 8; ++kk) {
            int k = lane * 8 + kk;
            const float* row = emb + k * DDIM;
            double dot = 0.0;
            #pragma unroll
            for (int c = 0; c < DDIM; ++c) dot = fma((double)x[c], (double)row[c], dot);
            float dotf = (float)dot;                  // == sgemm M within ~1e-9
            float t = x2 + e2[k];                     // fp32 add (quantizes at ulp(~64))
            float d = t - 2.0f * dotf;                // 2*dotf exact; one rounding
            if (d < bestd) { bestd = d; besti = k; }  // ascending k: first wins ties
        }
        // cross-lane min-reduce, tie -> smaller index (np.argmin first occurrence)
        for (int off = 32; off; off >>= 1) {
            double od_ = __shfl_down(bestd, off);
            float od = (float)od_;
            int   oi = __shfl_down(besti, off);
            if (od < bestd || (od == bestd && oi < besti)) { bestd = od; besti = oi; }
        }
        if (lane == 0) {
            int old = idx[g];
            if (besti != old) {
                atomicAdd(&counts[old], -1);
                atomicAdd(&counts[besti], 1);
                idx[g] = besti;
                out[OUT_IDX + g] = (float)besti;
            }
        }
    }
}

// -------------------- epilogue: z_q_st + loss partials (float4, few atomics) ----
__global__ __launch_bounds__(256) void k_epilogue(
        const float* __restrict__ z_e, const float* __restrict__ emb,
        const int* __restrict__ idx, float* __restrict__ out,
        float* __restrict__ slots) {
    int t = blockIdx.x * 256 + threadIdx.x;   // 1M threads, 4 elems each
    int e = t << 2;
    int p = e & 4095;                         // multiple of 4
    int c = (e >> 12) & 63;
    int b = e >> 18;
    int g = (b << 12) | p;

    int4   iv = *(const int4*)(idx + g);
    float4 ze = *(const float4*)(z_e + e);
    float d0 = emb[iv.x * DDIM + c] - ze.x;   // stop_gradient(z_q - z_e)
    float d1 = emb[iv.y * DDIM + c] - ze.y;
    float d2 = emb[iv.z * DDIM + c] - ze.z;
    float d3 = emb[iv.w * DDIM + c] - ze.w;
    float4 o;
    o.x = ze.x + d0; o.y = ze.y + d1; o.z = ze.z + d2; o.w = ze.w + d3;
    *(float4*)(out + e) = o;

    float sq = d0 * d0 + d1 * d1 + d2 * d2 + d3 * d3;
    #pragma unroll
    for (int off = 32; off; off >>= 1) sq += __shfl_down(sq, off);
    if ((threadIdx.x & 63) == 0) {
        int slot = (blockIdx.x * 4 + (threadIdx.x >> 6)) & 63;  // spread contention
        atomicAdd(&slots[slot * 16], sq);                        // 64B-padded slots
    }
}

// -------------------- final scalars: loss, perplexity --------------------
__global__ void k_final(const int* __restrict__ counts,
                        const float* __restrict__ slots,
                        float* __restrict__ out) {
    int t = threadIdx.x;  // 512 threads, 1 block
    float cnt = (float)counts[t];
    float pb = cnt * (1.0f / 65536.0f);
    float term = pb * logf(pb + 1e-10f);
    #pragma unroll
    for (int off = 32; off; off >>= 1) term += __shfl_down(term, off);
    __shared__ float ls[8];
    __shared__ float lsum;
    int lane = t & 63, w = t >> 6;
    if (lane == 0) ls[w] = term;
    if (w == 0) {                               // wave 0 reduces the 64 loss slots
        float s2 = slots[lane * 16];
        #pragma unroll
        for (int off = 32; off; off >>= 1) s2 += __shfl_down(s2, off);
        if (lane == 0) lsum = s2;
    }
    __syncthreads();
    if (t == 0) {
        float s = 0.0f;
        #pragma unroll
        for (int i = 0; i < 8; ++i) s += ls[i];
        out[OUT_PPL]  = expf(-s);
        out[OUT_LOSS] = 0.25f * (lsum / (float)NELEM);
    }
}

extern "C" void kernel_launch(void* const* d_in, const int* in_sizes, int n_in,
                              void* d_out, int out_size, void* d_ws, size_t ws_size,
                              hipStream_t stream) {
    const float* z_e = (const float*)d_in[0];
    const float* emb = (const float*)d_in[1];
    float* out = (float*)d_out;
    char* ws = (char*)d_ws;

    // ws layout
    int*   idx      = (int*)(ws);             // 65536 ints   [0, 262144)
    int*   flags    = (int*)(ws + 262144);    // 65536 ints   [262144, 524288)
    float* e2       = (float*)(ws + 524288);  // 512 floats   [524288, 526336)
    int*   nflag    = (int*)(ws + 526336);    // 1 int
    int*   counts   = (int*)(ws + 526400);    // 512 ints     [526400, 528448)
    float* slots    = (float*)(ws + 528448);  // 64 slots x 16 floats = 4096 B

    // zero accumulators: nflag + counts + slots  (ws is poisoned 0xAA every call)
    hipMemsetAsync(ws + 526336, 0, 532544 - 526336, stream);

    prep_e2<<<1, 512, 0, stream>>>(emb, e2);
    k_dist<<<NPIX / 128, 256, 0, stream>>>(z_e, emb, e2, idx, flags, nflag, counts, out);
    k_refine<<<256, 256, 0, stream>>>(z_e, emb, e2, idx, flags, nflag, counts, out);
    k_epilogue<<<NELEM / 1024, 256, 0, stream>>>(z_e, emb, idx, out, slots);
    k_final<<<1, 512, 0, stream>>>(counts, slots, out);
}

// Round 4
// 211.709 us; speedup vs baseline: 2.1054x; 1.2237x over previous
//
#include <hip/hip_runtime.h>

// Problem constants
#define BATCH 16
#define CH 64          // EMBEDDING_DIM
#define HW 4096        // 64*64
#define NPIX 65536     // BATCH*HW
#define KCODES 512
#define DDIM 64
#define NELEM 4194304  // NPIX*CH

// d_out layout (float32): [z_q_st: NELEM][loss: 1][ppl: 1][indices: NPIX]
#define OUT_LOSS 4194304
#define OUT_PPL  4194305
#define OUT_IDX  4194306

#define MARGIN 1e-4f

typedef short bf16x8 __attribute__((ext_vector_type(8)));
typedef float f32x4  __attribute__((ext_vector_type(4)));

// Force a value to be materialized (blocks fp-contract fusing mul into add,
// so squares round exactly like numpy's materialized flat*flat).
__device__ __forceinline__ float rnd(float s) {
    asm volatile("" : "+v"(s));
    return s;
}

__device__ __forceinline__ short f2bf(float f) {           // RNE fp32->bf16
    unsigned u = __builtin_bit_cast(unsigned, f);
    unsigned r = (u + 0x7fffu + ((u >> 16) & 1u)) >> 16;
    return (short)r;
}
__device__ __forceinline__ float bf2f(short s) {
    unsigned u = ((unsigned)(unsigned short)s) << 16;
    return __builtin_bit_cast(float, u);
}

// -------------------- prep: e2 (numpy pairwise) + fragment-ordered bf16 hi/lo codebook ---
// B packing: entry index = tn*128 + chunk*64 + lane, lane=(q<<4)|i:
//   code = tn*16+i, k = chunk*32 + q*8 + j  (j=0..7), 16B per entry.
__global__ void k_prep(const float* __restrict__ emb, float* __restrict__ e2,
                       bf16x8* __restrict__ Bh, bf16x8* __restrict__ Bl) {
    int gid = blockIdx.x * 256 + threadIdx.x;
    if (gid < 4096) {
        int tn = gid >> 7, rem = gid & 127;
        int chunk = (rem >> 6) & 1, q = (rem >> 4) & 3, i = rem & 15;
        int code = tn * 16 + i;
        int k0 = chunk * 32 + q * 8;
        const float* src = emb + code * DDIM + k0;
        bf16x8 h, l;
        #pragma unroll
        for (int j = 0; j < 8; ++j) {
            float v = src[j];
            short hh = f2bf(v);
            h[j] = hh;
            l[j] = f2bf(v - bf2f(hh));
        }
        Bh[gid] = h;
        Bl[gid] = l;
    } else if (gid < 4608) {
        int k = gid - 4096;
        const float* row = emb + k * DDIM;
        float r[8];
        #pragma unroll
        for (int j = 0; j < 8; ++j) { float v = row[j]; r[j] = rnd(v * v); }
        #pragma unroll
        for (int m = 1; m < 8; ++m)
            #pragma unroll
            for (int j = 0; j < 8; ++j) { float v = row[8 * m + j]; r[j] += rnd(v * v); }
        e2[k] = ((r[0] + r[1]) + (r[2] + r[3])) + ((r[4] + r[5]) + (r[6] + r[7]));
    }
}

// -------------------- MFMA distance/argmin kernel --------------------
// Block = 256 thr = 4 waves x 32 pixels = 128 pixels. Grid = 512.
// Split-precision: dot = Ah*Bh + Ah*Bl + Al*Bh  (error ~1e-5 << MARGIN).
__global__ __launch_bounds__(256, 2) void k_dist(
        const float* __restrict__ z_e,
        const bf16x8* __restrict__ Bh, const bf16x8* __restrict__ Bl,
        const float* __restrict__ e2g,
        int* __restrict__ idx, int* __restrict__ flags, int* __restrict__ nflag,
        int* __restrict__ counts, float* __restrict__ out) {
    __shared__ unsigned int AhU[128 * 36];   // [px][72 shorts] padded (+8) rows
    __shared__ unsigned int AlU[128 * 36];
    __shared__ float e2s[512];

    int t = threadIdx.x;
    int pxbase = blockIdx.x * 128;
    int batch = pxbase >> 12;
    int p0 = pxbase & 4095;
    const float* zb = z_e + (size_t)batch * (CH * HW) + p0;

    // stage A: 128 px x 64 ch, convert to bf16 hi/lo. short2-packed b32 writes.
    #pragma unroll
    for (int it = 0; it < 16; ++it) {
        int i = it * 256 + t;            // 4096 channel-pairs
        int cp = i >> 7;                 // 0..31 -> channels 2cp, 2cp+1
        int pp = i & 127;
        float v0 = zb[(2 * cp) * HW + pp];
        float v1 = zb[(2 * cp + 1) * HW + pp];
        short h0 = f2bf(v0), h1 = f2bf(v1);
        short l0 = f2bf(v0 - bf2f(h0)), l1 = f2bf(v1 - bf2f(h1));
        AhU[pp * 36 + cp] = (unsigned)(unsigned short)h0 | ((unsigned)(unsigned short)h1 << 16);
        AlU[pp * 36 + cp] = (unsigned)(unsigned short)l0 | ((unsigned)(unsigned short)l1 << 16);
    }
    e2s[t] = e2g[t];
    e2s[t + 256] = e2g[t + 256];
    __syncthreads();

    int w = t >> 6;
    int lane = t & 63;
    int col = lane & 15;
    int quad = lane >> 4;

    // A fragments: 2 M-tiles x 2 K-chunks x {hi,lo}; A[m=lane&15][k=quad*8+j]
    const short* Ahs = (const short*)AhU;
    const short* Als = (const short*)AlU;
    bf16x8 ah[2][2], al[2][2];
    #pragma unroll
    for (int mt = 0; mt < 2; ++mt) {
        int m = w * 32 + mt * 16 + col;
        #pragma unroll
        for (int ch = 0; ch < 2; ++ch) {
            int k = ch * 32 + quad * 8;
            ah[mt][ch] = *(const bf16x8*)(Ahs + m * 72 + k);
            al[mt][ch] = *(const bf16x8*)(Als + m * 72 + k);
        }
    }

    float m1[2][4], m2[2][4];
    int   i1[2][4];
    #pragma unroll
    for (int mt = 0; mt < 2; ++mt)
        #pragma unroll
        for (int r = 0; r < 4; ++r) { m1[mt][r] = 1e30f; m2[mt][r] = 1e30f; i1[mt][r] = 0; }

    for (int tn = 0; tn < 32; ++tn) {
        bf16x8 bh0 = Bh[tn * 128 + lane];
        bf16x8 bh1 = Bh[tn * 128 + 64 + lane];
        bf16x8 bl0 = Bl[tn * 128 + lane];
        bf16x8 bl1 = Bl[tn * 128 + 64 + lane];
        float e2v = e2s[tn * 16 + col];
        int n = tn * 16 + col;
        #pragma unroll
        for (int mt = 0; mt < 2; ++mt) {
            f32x4 acc = {0.f, 0.f, 0.f, 0.f};
            acc = __builtin_amdgcn_mfma_f32_16x16x32_bf16(ah[mt][0], bh0, acc, 0, 0, 0);
            acc = __builtin_amdgcn_mfma_f32_16x16x32_bf16(ah[mt][1], bh1, acc, 0, 0, 0);
            acc = __builtin_amdgcn_mfma_f32_16x16x32_bf16(ah[mt][0], bl0, acc, 0, 0, 0);
            acc = __builtin_amdgcn_mfma_f32_16x16x32_bf16(ah[mt][1], bl1, acc, 0, 0, 0);
            acc = __builtin_amdgcn_mfma_f32_16x16x32_bf16(al[mt][0], bh0, acc, 0, 0, 0);
            acc = __builtin_amdgcn_mfma_f32_16x16x32_bf16(al[mt][1], bh1, acc, 0, 0, 0);
            #pragma unroll
            for (int r = 0; r < 4; ++r) {
                float d = fmaf(-2.0f, acc[r], e2v);
                if (d < m1[mt][r])      { m2[mt][r] = m1[mt][r]; m1[mt][r] = d; i1[mt][r] = n; }
                else if (d < m2[mt][r]) { m2[mt][r] = d; }
            }
        }
    }

    // merge across the 16 lanes sharing a quad (different cols)
    #pragma unroll
    for (int off = 1; off < 16; off <<= 1) {
        #pragma unroll
        for (int mt = 0; mt < 2; ++mt)
            #pragma unroll
            for (int r = 0; r < 4; ++r) {
                float om1 = __shfl_xor(m1[mt][r], off);
                float om2 = __shfl_xor(m2[mt][r], off);
                int   oi  = __shfl_xor(i1[mt][r], off);
                if (om1 < m1[mt][r] || (om1 == m1[mt][r] && oi < i1[mt][r])) {
                    m2[mt][r] = fminf(m1[mt][r], om2);
                    m1[mt][r] = om1;
                    i1[mt][r] = oi;
                } else {
                    m2[mt][r] = fminf(m2[mt][r], om1);
                }
            }
    }

    if (col == 0) {
        #pragma unroll
        for (int mt = 0; mt < 2; ++mt)
            #pragma unroll
            for (int r = 0; r < 4; ++r) {
                int g = pxbase + w * 32 + mt * 16 + quad * 4 + r;
                int best = i1[mt][r];
                idx[g] = best;
                out[OUT_IDX + g] = (float)best;
                atomicAdd(&counts[best], 1);
                if (m2[mt][r] - m1[mt][r] < MARGIN) {
                    int pos = atomicAdd(nflag, 1);
                    flags[pos] = g;
                }
            }
    }
}

// -------------------- near-tie refinement: simulate numpy fp32 exactly --------------------
__global__ __launch_bounds__(256) void k_refine(
        const float* __restrict__ z_e, const float* __restrict__ emb,
        const float* __restrict__ e2,
        int* __restrict__ idx, const int* __restrict__ flags,
        const int* __restrict__ nflag,
        int* __restrict__ counts, float* __restrict__ out) {
    int n = nflag[0];
    int wave = (blockIdx.x * blockDim.x + threadIdx.x) >> 6;
    int lane = threadIdx.x & 63;
    int nwaves = (gridDim.x * blockDim.x) >> 6;

    for (int i = wave; i < n; i += nwaves) {
        int g = flags[i];
        int b = g >> 12;
        int p = g & 4095;
        const float* xp = z_e + (size_t)b * (CH * HW) + p;
        float x[DDIM];
        #pragma unroll
        for (int c = 0; c < DDIM; ++c) x[c] = xp[c * HW];

        // numpy pairwise sum of squares (n=64: 8 accumulators + tree combine)
        float r[8];
        #pragma unroll
        for (int j = 0; j < 8; ++j) r[j] = rnd(x[j] * x[j]);
        #pragma unroll
        for (int m = 1; m < 8; ++m)
            #pragma unroll
            for (int j = 0; j < 8; ++j) r[j] += rnd(x[8 * m + j] * x[8 * m + j]);
        float x2 = ((r[0] + r[1]) + (r[2] + r[3])) + ((r[4] + r[5]) + (r[6] + r[7]));

        float bestd = INFINITY;
        int besti = 1 << 30;
        for (int kk = 0; kk < 8; ++kk) {
            int k = lane * 8 + kk;
            const float* row = emb + k * DDIM;
            double dot = 0.0;
            #pragma unroll
            for (int c = 0; c < DDIM; ++c) dot = fma((double)x[c], (double)row[c], dot);
            float dotf = (float)dot;                  // == sgemm M within ~1e-9
            float tt = x2 + e2[k];                    // fp32 add (quantizes at ulp(~64))
            float d = tt - 2.0f * dotf;               // one rounding
            if (d < bestd) { bestd = d; besti = k; }  // ascending k: first wins ties
        }
        for (int off = 32; off; off >>= 1) {
            double od_ = __shfl_down((double)bestd, off);
            float od = (float)od_;
            int   oi = __shfl_down(besti, off);
            if (od < bestd || (od == bestd && oi < besti)) { bestd = od; besti = oi; }
        }
        if (lane == 0) {
            int old = idx[g];
            if (besti != old) {
                atomicAdd(&counts[old], -1);
                atomicAdd(&counts[besti], 1);
                idx[g] = besti;
                out[OUT_IDX + g] = (float)besti;
            }
        }
    }
}

// -------------------- epilogue: z_q_st + loss partials (float4, few atomics) ----
__global__ __launch_bounds__(256) void k_epilogue(
        const float* __restrict__ z_e, const float* __restrict__ emb,
        const int* __restrict__ idx, float* __restrict__ out,
        float* __restrict__ slots) {
    int t = blockIdx.x * 256 + threadIdx.x;   // 1M threads, 4 elems each
    int e = t << 2;
    int p = e & 4095;                         // multiple of 4
    int c = (e >> 12) & 63;
    int b = e >> 18;
    int g = (b << 12) | p;

    int4   iv = *(const int4*)(idx + g);
    float4 ze = *(const float4*)(z_e + e);
    float d0 = emb[iv.x * DDIM + c] - ze.x;   // stop_gradient(z_q - z_e)
    float d1 = emb[iv.y * DDIM + c] - ze.y;
    float d2 = emb[iv.z * DDIM + c] - ze.z;
    float d3 = emb[iv.w * DDIM + c] - ze.w;
    float4 o;
    o.x = ze.x + d0; o.y = ze.y + d1; o.z = ze.z + d2; o.w = ze.w + d3;
    *(float4*)(out + e) = o;

    float sq = d0 * d0 + d1 * d1 + d2 * d2 + d3 * d3;
    #pragma unroll
    for (int off = 32; off; off >>= 1) sq += __shfl_down(sq, off);
    if ((threadIdx.x & 63) == 0) {
        int slot = (blockIdx.x * 4 + (threadIdx.x >> 6)) & 63;  // spread contention
        atomicAdd(&slots[slot * 16], sq);                        // 64B-padded slots
    }
}

// -------------------- final scalars: loss, perplexity --------------------
__global__ void k_final(const int* __restrict__ counts,
                        const float* __restrict__ slots,
                        float* __restrict__ out) {
    int t = threadIdx.x;  // 512 threads, 1 block
    float cnt = (float)counts[t];
    float pb = cnt * (1.0f / 65536.0f);
    float term = pb * logf(pb + 1e-10f);
    #pragma unroll
    for (int off = 32; off; off >>= 1) term += __shfl_down(term, off);
    __shared__ float ls[8];
    __shared__ float lsum;
    int lane = t & 63, w = t >> 6;
    if (lane == 0) ls[w] = term;
    if (w == 0) {                               // wave 0 reduces the 64 loss slots
        float s2 = slots[lane * 16];
        #pragma unroll
        for (int off = 32; off; off >>= 1) s2 += __shfl_down(s2, off);
        if (lane == 0) lsum = s2;
    }
    __syncthreads();
    if (t == 0) {
        float s = 0.0f;
        #pragma unroll
        for (int i = 0; i < 8; ++i) s += ls[i];
        out[OUT_PPL]  = expf(-s);
        out[OUT_LOSS] = 0.25f * (lsum / (float)NELEM);
    }
}

extern "C" void kernel_launch(void* const* d_in, const int* in_sizes, int n_in,
                              void* d_out, int out_size, void* d_ws, size_t ws_size,
                              hipStream_t stream) {
    const float* z_e = (const float*)d_in[0];
    const float* emb = (const float*)d_in[1];
    float* out = (float*)d_out;
    char* ws = (char*)d_ws;

    // ws layout
    int*    idx      = (int*)(ws);             // 65536 ints   [0, 262144)
    int*    flags    = (int*)(ws + 262144);    // 65536 ints   [262144, 524288)
    float*  e2       = (float*)(ws + 524288);  // 512 floats   [524288, 526336)
    int*    nflag    = (int*)(ws + 526336);    // 1 int
    int*    counts   = (int*)(ws + 526400);    // 512 ints     [526400, 528448)
    float*  slots    = (float*)(ws + 528448);  // 64 x 16 floats = 4096 B
    bf16x8* Bh       = (bf16x8*)(ws + 532544); // 4096 x 16 B = 64 KB
    bf16x8* Bl       = (bf16x8*)(ws + 598080); // 4096 x 16 B = 64 KB

    // zero accumulators: nflag + counts + slots  (ws is poisoned 0xAA every call)
    hipMemsetAsync(ws + 526336, 0, 532544 - 526336, stream);

    k_prep<<<18, 256, 0, stream>>>(emb, e2, Bh, Bl);
    k_dist<<<NPIX / 128, 256, 0, stream>>>(z_e, Bh, Bl, e2, idx, flags, nflag, counts, out);
    k_refine<<<256, 256, 0, stream>>>(z_e, emb, e2, idx, flags, nflag, counts, out);
    k_epilogue<<<NELEM / 1024, 256, 0, stream>>>(z_e, emb, idx, out, slots);
    k_final<<<1, 512, 0, stream>>>(counts, slots, out);
}